// Round 6
// baseline (405.195 us; speedup 1.0000x reference)
//
#include <hip/hip_runtime.h>
#include <math.h>

#define NEG_SLOPE 0.2f
#define L2E 1.4426950408889634f
#define NPB_SHIFT 8              // nodes per bucket = 256
#define NBMAX 512                // supports N <= 131072
#define SC_EDGES 4096            // edges staged per scatter block

__device__ __forceinline__ float bf2f(unsigned short u) {
    return __uint_as_float(((unsigned int)u) << 16);
}
__device__ __forceinline__ unsigned short f2bf(float f) {  // RNE
    unsigned int u = __float_as_uint(f);
    u += 0x7FFFu + ((u >> 16) & 1u);
    return (unsigned short)(u >> 16);
}

// ---------------------------------------------------------------------------
// Pass 0: global coarse-bucket histogram (LDS-accumulated)
// ---------------------------------------------------------------------------
__global__ void k_hist(const int* __restrict__ dstA, int E, int NB,
                       int* __restrict__ gcount) {
    __shared__ int hist[NBMAX];
    for (int i = threadIdx.x; i < NBMAX; i += blockDim.x) hist[i] = 0;
    __syncthreads();
    int stride = gridDim.x * blockDim.x;
    for (int i = blockIdx.x * blockDim.x + threadIdx.x; i < E; i += stride)
        atomicAdd(&hist[dstA[i] >> NPB_SHIFT], 1);
    __syncthreads();
    for (int b = threadIdx.x; b < NB; b += blockDim.x) {
        int c = hist[b];
        if (c) atomicAdd(&gcount[b], c);
    }
}

// ---------------------------------------------------------------------------
// Pass 0b: scan bucket counts -> bucket_start[NB+1]; init global cursors
// ---------------------------------------------------------------------------
__global__ void k_bscan(const int* __restrict__ gcount, int NB,
                        int* __restrict__ bucket_start, int* __restrict__ cursor_g) {
    __shared__ int s[NBMAX];
    int t = threadIdx.x;
    int v = (t < NB) ? gcount[t] : 0;
    s[t] = v;
    __syncthreads();
    for (int off = 1; off < NBMAX; off <<= 1) {
        int u = (t >= off) ? s[t - off] : 0;
        __syncthreads();
        s[t] += u;
        __syncthreads();
    }
    int ex = s[t] - v;
    if (t < NB) { bucket_start[t] = ex; cursor_g[t] = ex; }
    if (t == NB - 1) bucket_start[NB] = ex + v;
}

// ---------------------------------------------------------------------------
// Pass 1: scatter edges into bucket regions, LDS-staged so global writes are
// contiguous per bucket segment.  payload = (dst<<32) | src
// ---------------------------------------------------------------------------
__global__ void k_scatter(const int* __restrict__ srcA, const int* __restrict__ dstA,
                          int E, int NB, int* __restrict__ cursor_g,
                          unsigned long long* __restrict__ payload) {
    __shared__ unsigned long long stage[SC_EDGES];
    __shared__ int hist[NBMAX], scanb[NBMAX], cur2[NBMAX], gbase[NBMAX];
    __shared__ int ssum[256];
    const int ITER = SC_EDGES / 256;
    int t = threadIdx.x;
    int base = blockIdx.x * SC_EDGES;
    int cnt = E - base; if (cnt > SC_EDGES) cnt = SC_EDGES;

    for (int i = t; i < NBMAX; i += 256) hist[i] = 0;
    __syncthreads();
    for (int k = 0; k < ITER; ++k) {
        int j = k * 256 + t;
        if (j < cnt) atomicAdd(&hist[dstA[base + j] >> NPB_SHIFT], 1);
    }
    __syncthreads();
    int a0 = hist[2 * t], a1 = hist[2 * t + 1];
    ssum[t] = a0 + a1;
    __syncthreads();
    for (int off = 1; off < 256; off <<= 1) {
        int u = (t >= off) ? ssum[t - off] : 0;
        __syncthreads();
        ssum[t] += u;
        __syncthreads();
    }
    int ex = ssum[t] - (a0 + a1);
    scanb[2 * t] = ex;
    scanb[2 * t + 1] = ex + a0;
    cur2[2 * t] = 0;
    cur2[2 * t + 1] = 0;
    __syncthreads();
    for (int b = t; b < NB; b += 256) {
        int c = hist[b];
        gbase[b] = c ? atomicAdd(&cursor_g[b], c) : 0;
    }
    __syncthreads();
    for (int k = 0; k < ITER; ++k) {
        int j = k * 256 + t;
        if (j < cnt) {
            int s = srcA[base + j];
            int d = dstA[base + j];
            int b = d >> NPB_SHIFT;
            int pos = scanb[b] + atomicAdd(&cur2[b], 1);
            stage[pos] = ((unsigned long long)(unsigned int)d << 32) | (unsigned int)s;
        }
    }
    __syncthreads();
    for (int k = 0; k < ITER; ++k) {
        int j = k * 256 + t;
        if (j < cnt) {
            unsigned long long p = stage[j];
            int b = (int)(p >> (32 + NPB_SHIFT));
            payload[gbase[b] + (j - scanb[b])] = p;
        }
    }
}

// ---------------------------------------------------------------------------
// Pass 2: one 1024-thread workgroup per bucket -> exact CSR (deg, rows, csr).
// ---------------------------------------------------------------------------
__global__ void k_buildcsr(const unsigned long long* __restrict__ payload,
                           const int* __restrict__ bucket_start, int N,
                           int* __restrict__ deg, int* __restrict__ rows,
                           int* __restrict__ csr) {
    __shared__ int hist[256], scanb[256], cur[256];
    int b = blockIdx.x;
    int t = threadIdx.x;
    int bs = bucket_start[b], be = bucket_start[b + 1];
    int nodeBase = b << NPB_SHIFT;
    int nNodes = N - nodeBase; if (nNodes > 256) nNodes = 256;
    if (t < 256) hist[t] = 0;
    __syncthreads();
    for (int i = bs + t; i < be; i += 1024)
        atomicAdd(&hist[(int)(payload[i] >> 32) & 255], 1);
    __syncthreads();
    if (t < 256) {
        int own = hist[t];
        scanb[t] = own;
    }
    __syncthreads();
    for (int off = 1; off < 256; off <<= 1) {
        int u = 0;
        if (t < 256 && t >= off) u = scanb[t - off];
        __syncthreads();
        if (t < 256) scanb[t] += u;
        __syncthreads();
    }
    if (t < 256) {
        int own = hist[t];
        int ex = scanb[t] - own;
        if (t < nNodes) { deg[nodeBase + t] = own; rows[nodeBase + t] = bs + ex; }
        cur[t] = ex;
    }
    __syncthreads();
    for (int i = bs + t; i < be; i += 1024) {
        unsigned long long p = payload[i];
        int dl = (int)(p >> 32) & 255;
        int slot = atomicAdd(&cur[dl], 1);
        csr[bs + slot] = (int)(unsigned int)p;
    }
}

// ---------------------------------------------------------------------------
// Layer 1 projection: rec[n] = 128 B of bf16 feats (full-line writes);
// as1/ad1 compact fp32 arrays (L2-resident), pre-scaled by log2(e).
// ---------------------------------------------------------------------------
__global__ void k_h1(const float* __restrict__ x, const float* __restrict__ W1,
                     const float* __restrict__ a_src, const float* __restrict__ a_dst,
                     int N, char* __restrict__ rec,
                     float* __restrict__ as1, float* __restrict__ ad1) {
    __shared__ float Ws[7 * 64];
    int tid = threadIdx.x;
    for (int i = tid; i < 7 * 64; i += blockDim.x) Ws[i] = W1[i];
    __syncthreads();
    int n = blockIdx.x * 4 + (tid >> 6);
    int lane = tid & 63;
    if (n >= N) return;
    float xv[7];
#pragma unroll
    for (int k = 0; k < 7; ++k) xv[k] = x[n * 7 + k];
    float hv = 0.f;
#pragma unroll
    for (int k = 0; k < 7; ++k) hv += xv[k] * Ws[k * 64 + lane];
    ((unsigned short*)(rec + ((size_t)n << 7)))[lane] = f2bf(hv);
    float ps = hv * a_src[lane];
    float pd = hv * a_dst[lane];
#pragma unroll
    for (int off = 1; off < 8; off <<= 1) {
        ps += __shfl_xor(ps, off);
        pd += __shfl_xor(pd, off);
    }
    if ((lane & 7) == 0) {
        as1[n * 8 + (lane >> 3)] = ps * L2E;   // exp(x) == exp2(x*L2E)
        ad1[n * 8 + (lane >> 3)] = pd * L2E;
    }
}

// ---------------------------------------------------------------------------
// Layer 1 aggregation + bias + ELU, fused with layer-2 projection (64->2).
// Batched gather: 16 scalar indices (readlane), then 16 alpha + 16 feat loads
// issued back-to-back (explicit arrays -> all in flight), then compute.
// ---------------------------------------------------------------------------
__global__ void k_agg1(const char* __restrict__ rec, const float* __restrict__ as1,
                       const float* __restrict__ ad1,
                       const int* __restrict__ deg, const int* __restrict__ rows,
                       const int* __restrict__ csr, const float* __restrict__ b1,
                       const float* __restrict__ W2, const float* __restrict__ as2w,
                       const float* __restrict__ ad2w, int N,
                       float4* __restrict__ pack) {
    int n = blockIdx.x * 4 + (threadIdx.x >> 6);
    int lane = threadIdx.x & 63;
    if (n >= N) return;
    n = __builtin_amdgcn_readfirstlane(n);
    int h = lane >> 3;
    int lane2 = lane * 2;            // feat byte-offset (loop-invariant)
    float adv = ad1[n * 8 + h];
    int d = __builtin_amdgcn_readfirstlane(deg[n]);
    int start = __builtin_amdgcn_readfirstlane(rows[n]);
    float acc = 0.f, den = 0.f;
    int c = 0;
    int nfull = d & ~15;
    for (; c < nfull; c += 16) {
        int idxv = csr[start + c + (lane & 15)];   // 16 indices, wave-broadcast
        int sreg[16];
#pragma unroll
        for (int k = 0; k < 16; ++k)
            sreg[k] = __builtin_amdgcn_readlane(idxv, k);   // SGPR by construction
        float ev[16];
#pragma unroll
        for (int k = 0; k < 16; ++k) {
            const float* ap = as1 + (size_t)(unsigned)sreg[k] * 8;
            ev[k] = ap[h];
        }
        unsigned short uv[16];
#pragma unroll
        for (int k = 0; k < 16; ++k) {
            const char* rb = rec + ((size_t)(unsigned)sreg[k] << 7);
            uv[k] = *(const unsigned short*)(rb + lane2);
        }
#pragma unroll
        for (int k = 0; k < 16; ++k) {
            float t = ev[k] + adv;
            float w = __builtin_amdgcn_exp2f(fmaxf(t, NEG_SLOPE * t));
            den += w;
            acc = fmaf(w, bf2f(uv[k]), acc);
        }
    }
    for (; c < d; ++c) {
        int s = __builtin_amdgcn_readfirstlane(csr[start + c]);
        const float* ap = as1 + (size_t)(unsigned)s * 8;
        const char* rb = rec + ((size_t)(unsigned)s << 7);
        float t = ap[h] + adv;
        float w = __builtin_amdgcn_exp2f(fmaxf(t, NEG_SLOPE * t));
        den += w;
        acc = fmaf(w, bf2f(*(const unsigned short*)(rb + lane2)), acc);
    }
    {   // self loop
        const char* rb = rec + ((size_t)n << 7);
        float t = as1[n * 8 + h] + adv;
        float w = __builtin_amdgcn_exp2f(fmaxf(t, NEG_SLOPE * t));
        den += w;
        acc = fmaf(w, bf2f(*(const unsigned short*)(rb + lane2)), acc);
    }
    float o = acc / den + b1[lane];
    float v = o > 0.f ? o : (__expf(o) - 1.f);  // ELU
    float p0 = v * W2[lane * 2 + 0];
    float p1 = v * W2[lane * 2 + 1];
#pragma unroll
    for (int off = 1; off < 64; off <<= 1) {
        p0 += __shfl_xor(p0, off);
        p1 += __shfl_xor(p1, off);
    }
    if (lane == 0) {
        float4 pk;
        pk.x = p0;
        pk.y = p1;
        pk.z = (p0 * as2w[0] + p1 * as2w[1]) * L2E;
        pk.w = (p0 * ad2w[0] + p1 * ad2w[1]) * L2E;
        pack[n] = pk;
    }
}

// ---------------------------------------------------------------------------
// Layer 2 aggregation + bias + log_softmax: single float4 gather per edge.
// ---------------------------------------------------------------------------
__global__ void k_agg2(const float4* __restrict__ pack, const int* __restrict__ deg,
                       const int* __restrict__ rows, const int* __restrict__ csr,
                       const float* __restrict__ b2, int N, float* __restrict__ out) {
    int n = blockIdx.x * 4 + (threadIdx.x >> 6);
    int lane = threadIdx.x & 63;
    if (n >= N) return;
    n = __builtin_amdgcn_readfirstlane(n);
    float4 self = pack[n];
    float adv = self.w;
    int d = __builtin_amdgcn_readfirstlane(deg[n]);
    int start = __builtin_amdgcn_readfirstlane(rows[n]);
    float den = 0.f, a0 = 0.f, a1 = 0.f;
    for (int i = lane; i < d; i += 64) {
        int src = csr[start + i];
        float4 q = pack[src];
        float t = q.z + adv;
        float w = __builtin_amdgcn_exp2f(fmaxf(t, NEG_SLOPE * t));
        den += w;
        a0 += w * q.x;
        a1 += w * q.y;
    }
#pragma unroll
    for (int off = 1; off < 64; off <<= 1) {
        den += __shfl_xor(den, off);
        a0  += __shfl_xor(a0, off);
        a1  += __shfl_xor(a1, off);
    }
    if (lane == 0) {
        float t = self.z + adv;                      // self loop
        float w = __builtin_amdgcn_exp2f(fmaxf(t, NEG_SLOPE * t));
        den += w;
        a0 += w * self.x;
        a1 += w * self.y;
        float o0 = a0 / den + b2[0];
        float o1 = a1 / den + b2[1];
        float m = fmaxf(o0, o1);
        float lse = m + logf(__expf(o0 - m) + __expf(o1 - m));
        out[n * 2 + 0] = o0 - lse;
        out[n * 2 + 1] = o1 - lse;
    }
}

// ---------------------------------------------------------------------------
extern "C" void kernel_launch(void* const* d_in, const int* in_sizes, int n_in,
                              void* d_out, int out_size, void* d_ws, size_t ws_size,
                              hipStream_t stream) {
    const float* x     = (const float*)d_in[0];
    const int*   ei    = (const int*)d_in[1];
    const float* W1    = (const float*)d_in[2];
    const float* as1w  = (const float*)d_in[3];
    const float* ad1w  = (const float*)d_in[4];
    const float* b1    = (const float*)d_in[5];
    const float* W2    = (const float*)d_in[6];
    const float* as2w  = (const float*)d_in[7];
    const float* ad2w  = (const float*)d_in[8];
    const float* b2    = (const float*)d_in[9];
    float* out = (float*)d_out;

    const int N = in_sizes[0] / 7;
    const int E = in_sizes[1] / 2;
    const int* srcA = ei;
    const int* dstA = ei + E;
    const int NB = (N + ((1 << NPB_SHIFT) - 1)) >> NPB_SHIFT;

    size_t off = 0;
    auto alloc = [&](size_t bytes) -> void* {
        void* p = (char*)d_ws + off;
        off += (bytes + 255) & ~(size_t)255;
        return p;
    };
    // payload (8B/edge) is dead after k_buildcsr; rec (128B/node) aliases it.
    size_t payload_bytes = (size_t)E * 8;
    size_t rec_bytes = (size_t)N * 128;
    unsigned long long* payload =
        (unsigned long long*)alloc(payload_bytes > rec_bytes ? payload_bytes : rec_bytes);
    char* rec = (char*)payload;
    float* as1  = (float*)alloc((size_t)N * 8 * 4);
    float* ad1  = (float*)alloc((size_t)N * 8 * 4);
    float4* pack = (float4*)alloc((size_t)N * 16);
    int*   deg  = (int*)alloc((size_t)N * 4);
    int*   rows = (int*)alloc((size_t)N * 4);
    int*   csr  = (int*)alloc((size_t)E * 4);
    int*   gcount       = (int*)alloc(NBMAX * 4);
    int*   bucket_start = (int*)alloc((NBMAX + 1) * 4);
    int*   cursor_g     = (int*)alloc(NBMAX * 4);

    hipMemsetAsync(gcount, 0, NBMAX * 4, stream);

    const int nb = (N + 3) / 4;
    const int sb = (E + SC_EDGES - 1) / SC_EDGES;

    k_hist<<<1024, 256, 0, stream>>>(dstA, E, NB, gcount);
    k_bscan<<<1, NBMAX, 0, stream>>>(gcount, NB, bucket_start, cursor_g);
    k_scatter<<<sb, 256, 0, stream>>>(srcA, dstA, E, NB, cursor_g, payload);
    k_buildcsr<<<NB, 1024, 0, stream>>>(payload, bucket_start, N, deg, rows, csr);

    k_h1<<<nb, 256, 0, stream>>>(x, W1, as1w, ad1w, N, rec, as1, ad1);
    k_agg1<<<nb, 256, 0, stream>>>(rec, as1, ad1, deg, rows, csr, b1,
                                   W2, as2w, ad2w, N, pack);
    k_agg2<<<nb, 256, 0, stream>>>(pack, deg, rows, csr, b2, N, out);
}

// Round 7
// 327.741 us; speedup vs baseline: 1.2363x; 1.2363x over previous
//
#include <hip/hip_runtime.h>
#include <math.h>

#define NEG_SLOPE 0.2f
#define L2E 1.4426950408889634f
#define NPB_SHIFT 8              // nodes per bucket = 256
#define NBMAX 512                // supports N <= 131072 (and N < 2^24 for packing)
#define SC_EDGES 8192            // edges per scatter block (256 thr * 32)

__device__ __forceinline__ float bf2f(unsigned short u) {
    return __uint_as_float(((unsigned int)u) << 16);
}
__device__ __forceinline__ unsigned short f2bf(float f) {  // RNE
    unsigned int u = __float_as_uint(f);
    u += 0x7FFFu + ((u >> 16) & 1u);
    return (unsigned short)(u >> 16);
}

// ---------------------------------------------------------------------------
// Pass 0: global coarse-bucket histogram (LDS-accumulated)
// ---------------------------------------------------------------------------
__global__ void k_hist(const int* __restrict__ dstA, int E, int NB,
                       int* __restrict__ gcount) {
    __shared__ int hist[NBMAX];
    for (int i = threadIdx.x; i < NBMAX; i += blockDim.x) hist[i] = 0;
    __syncthreads();
    int stride = gridDim.x * blockDim.x;
    for (int i = blockIdx.x * blockDim.x + threadIdx.x; i < E; i += stride)
        atomicAdd(&hist[dstA[i] >> NPB_SHIFT], 1);
    __syncthreads();
    for (int b = threadIdx.x; b < NB; b += blockDim.x) {
        int c = hist[b];
        if (c) atomicAdd(&gcount[b], c);
    }
}

// ---------------------------------------------------------------------------
// Pass 0b: scan bucket counts -> bucket_start[NB+1]; init global cursors
// ---------------------------------------------------------------------------
__global__ void k_bscan(const int* __restrict__ gcount, int NB,
                        int* __restrict__ bucket_start, int* __restrict__ cursor_g) {
    __shared__ int s[NBMAX];
    int t = threadIdx.x;
    int v = (t < NB) ? gcount[t] : 0;
    s[t] = v;
    __syncthreads();
    for (int off = 1; off < NBMAX; off <<= 1) {
        int u = (t >= off) ? s[t - off] : 0;
        __syncthreads();
        s[t] += u;
        __syncthreads();
    }
    int ex = s[t] - v;
    if (t < NB) { bucket_start[t] = ex; cursor_g[t] = ex; }
    if (t == NB - 1) bucket_start[NB] = ex + v;
}

// ---------------------------------------------------------------------------
// Pass 1: bucket scatter, direct ranked writes (no staging, no block scan).
// payload = (dst&255)<<24 | src   (4 B/edge; requires src < 2^24)
// Per (block,bucket) segment ~16 edges = 64 B -> ~1 line per segment.
// ---------------------------------------------------------------------------
__global__ void k_scatter(const int* __restrict__ srcA, const int* __restrict__ dstA,
                          int E, int NB, int* __restrict__ cursor_g,
                          unsigned int* __restrict__ payload) {
    __shared__ int hist[NBMAX], gbase[NBMAX], cur[NBMAX];
    const int ITER = SC_EDGES / 256;
    int t = threadIdx.x;
    int base = blockIdx.x * SC_EDGES;
    int cnt = E - base; if (cnt > SC_EDGES) cnt = SC_EDGES;

    for (int i = t; i < NBMAX; i += 256) hist[i] = 0;
    __syncthreads();
#pragma unroll
    for (int k = 0; k < ITER; ++k) {
        int j = k * 256 + t;
        if (j < cnt) atomicAdd(&hist[dstA[base + j] >> NPB_SHIFT], 1);
    }
    __syncthreads();
    for (int b = t; b < NBMAX; b += 256) {
        int c = hist[b];
        gbase[b] = c ? atomicAdd(&cursor_g[b], c) : 0;
        cur[b] = 0;
    }
    __syncthreads();
#pragma unroll
    for (int k = 0; k < ITER; ++k) {
        int j = k * 256 + t;
        if (j < cnt) {
            int d = dstA[base + j];
            int s = srcA[base + j];
            int b = d >> NPB_SHIFT;
            int r = atomicAdd(&cur[b], 1);
            payload[gbase[b] + r] =
                ((unsigned int)(d & ((1 << NPB_SHIFT) - 1)) << 24) | (unsigned int)s;
        }
    }
}

// ---------------------------------------------------------------------------
// Pass 2: one 1024-thread workgroup per bucket -> exact CSR (deg, rows, csr).
// ---------------------------------------------------------------------------
__global__ void k_buildcsr(const unsigned int* __restrict__ payload,
                           const int* __restrict__ bucket_start, int N,
                           int* __restrict__ deg, int* __restrict__ rows,
                           int* __restrict__ csr) {
    __shared__ int hist[256], scanb[256], cur[256];
    int b = blockIdx.x;
    int t = threadIdx.x;
    int bs = bucket_start[b], be = bucket_start[b + 1];
    int nodeBase = b << NPB_SHIFT;
    int nNodes = N - nodeBase; if (nNodes > 256) nNodes = 256;
    if (t < 256) hist[t] = 0;
    __syncthreads();
    for (int i = bs + t; i < be; i += 1024)
        atomicAdd(&hist[payload[i] >> 24], 1);
    __syncthreads();
    if (t < 256) scanb[t] = hist[t];
    __syncthreads();
    for (int off = 1; off < 256; off <<= 1) {
        int u = 0;
        if (t < 256 && t >= off) u = scanb[t - off];
        __syncthreads();
        if (t < 256) scanb[t] += u;
        __syncthreads();
    }
    if (t < 256) {
        int own = hist[t];
        int ex = scanb[t] - own;
        if (t < nNodes) { deg[nodeBase + t] = own; rows[nodeBase + t] = bs + ex; }
        cur[t] = ex;
    }
    __syncthreads();
    for (int i = bs + t; i < be; i += 1024) {
        unsigned int p = payload[i];
        int slot = atomicAdd(&cur[p >> 24], 1);
        csr[bs + slot] = (int)(p & 0xFFFFFFu);
    }
}

// ---------------------------------------------------------------------------
// Layer 1 projection into 256-B records (everything an edge touches, one block):
//   rec[n] bytes [0,128)  : 64 x bf16 features
//   rec[n] bytes [128,160): 8 x fp32 src-alphas, pre-scaled by log2(e)
// ad1 (dst-alphas, pre-scaled) separate (touched once per node, not per edge).
// ---------------------------------------------------------------------------
__global__ void k_h1(const float* __restrict__ x, const float* __restrict__ W1,
                     const float* __restrict__ a_src, const float* __restrict__ a_dst,
                     int N, char* __restrict__ rec, float* __restrict__ ad1) {
    __shared__ float Ws[7 * 64];
    int tid = threadIdx.x;
    for (int i = tid; i < 7 * 64; i += blockDim.x) Ws[i] = W1[i];
    __syncthreads();
    int n = blockIdx.x * 4 + (tid >> 6);
    int lane = tid & 63;
    if (n >= N) return;
    float xv[7];
#pragma unroll
    for (int k = 0; k < 7; ++k) xv[k] = x[n * 7 + k];
    float hv = 0.f;
#pragma unroll
    for (int k = 0; k < 7; ++k) hv += xv[k] * Ws[k * 64 + lane];
    char* rb = rec + ((size_t)n << 8);
    ((unsigned short*)rb)[lane] = f2bf(hv);
    float ps = hv * a_src[lane];
    float pd = hv * a_dst[lane];
#pragma unroll
    for (int off = 1; off < 8; off <<= 1) {
        ps += __shfl_xor(ps, off);
        pd += __shfl_xor(pd, off);
    }
    if ((lane & 7) == 0) {
        ((float*)(rb + 128))[lane >> 3] = ps * L2E;  // exp(x) == exp2(x*L2E)
        ad1[n * 8 + (lane >> 3)] = pd * L2E;
    }
}

// ---------------------------------------------------------------------------
// Layer 1 aggregation + bias + ELU, fused with layer-2 projection (64->2).
// Round-5 proven form: scalar record base serves both per-edge loads (one
// contiguous 256-B block per edge); interleaved load/compute 16-unroll.
// ---------------------------------------------------------------------------
__global__ void k_agg1(const char* __restrict__ rec, const float* __restrict__ ad1,
                       const int* __restrict__ deg, const int* __restrict__ rows,
                       const int* __restrict__ csr, const float* __restrict__ b1,
                       const float* __restrict__ W2, const float* __restrict__ as2w,
                       const float* __restrict__ ad2w, int N,
                       float4* __restrict__ pack) {
    int n = blockIdx.x * 4 + (threadIdx.x >> 6);
    int lane = threadIdx.x & 63;
    if (n >= N) return;
    n = __builtin_amdgcn_readfirstlane(n);
    int h = lane >> 3;
    int lane2 = lane * 2;            // feat byte-offset (loop-invariant)
    int aoff = 128 + (h << 2);       // alpha byte-offset (loop-invariant)
    float adv = ad1[n * 8 + h];
    int d = __builtin_amdgcn_readfirstlane(deg[n]);
    int start = __builtin_amdgcn_readfirstlane(rows[n]);
    float acc = 0.f, den = 0.f;
    int c = 0;
    int nfull = d & ~15;
    for (; c < nfull; c += 16) {
        int idxv = csr[start + c + (lane & 15)];   // 16 indices, wave-broadcast
#pragma unroll
        for (int k = 0; k < 16; ++k) {
            int s = __builtin_amdgcn_readlane(idxv, k);  // SGPR by construction
            const char* rb = rec + ((size_t)(unsigned)s << 8);
            float e = *(const float*)(rb + aoff);
            float f = bf2f(*(const unsigned short*)(rb + lane2));
            float t = e + adv;
            float w = __builtin_amdgcn_exp2f(fmaxf(t, NEG_SLOPE * t));
            den += w;
            acc = fmaf(w, f, acc);
        }
    }
    for (; c < d; ++c) {
        int s = __builtin_amdgcn_readfirstlane(csr[start + c]);
        const char* rb = rec + ((size_t)(unsigned)s << 8);
        float e = *(const float*)(rb + aoff);
        float f = bf2f(*(const unsigned short*)(rb + lane2));
        float t = e + adv;
        float w = __builtin_amdgcn_exp2f(fmaxf(t, NEG_SLOPE * t));
        den += w;
        acc = fmaf(w, f, acc);
    }
    {   // self loop
        const char* rb = rec + ((size_t)n << 8);
        float e = *(const float*)(rb + aoff);
        float f = bf2f(*(const unsigned short*)(rb + lane2));
        float t = e + adv;
        float w = __builtin_amdgcn_exp2f(fmaxf(t, NEG_SLOPE * t));
        den += w;
        acc = fmaf(w, f, acc);
    }
    float o = acc / den + b1[lane];
    float v = o > 0.f ? o : (__expf(o) - 1.f);  // ELU
    float p0 = v * W2[lane * 2 + 0];
    float p1 = v * W2[lane * 2 + 1];
#pragma unroll
    for (int off = 1; off < 64; off <<= 1) {
        p0 += __shfl_xor(p0, off);
        p1 += __shfl_xor(p1, off);
    }
    if (lane == 0) {
        float4 pk;
        pk.x = p0;
        pk.y = p1;
        pk.z = (p0 * as2w[0] + p1 * as2w[1]) * L2E;
        pk.w = (p0 * ad2w[0] + p1 * ad2w[1]) * L2E;
        pack[n] = pk;
    }
}

// ---------------------------------------------------------------------------
// Layer 2 aggregation + bias + log_softmax: single float4 gather per edge.
// ---------------------------------------------------------------------------
__global__ void k_agg2(const float4* __restrict__ pack, const int* __restrict__ deg,
                       const int* __restrict__ rows, const int* __restrict__ csr,
                       const float* __restrict__ b2, int N, float* __restrict__ out) {
    int n = blockIdx.x * 4 + (threadIdx.x >> 6);
    int lane = threadIdx.x & 63;
    if (n >= N) return;
    n = __builtin_amdgcn_readfirstlane(n);
    float4 self = pack[n];
    float adv = self.w;
    int d = __builtin_amdgcn_readfirstlane(deg[n]);
    int start = __builtin_amdgcn_readfirstlane(rows[n]);
    float den = 0.f, a0 = 0.f, a1 = 0.f;
    for (int i = lane; i < d; i += 64) {
        int src = csr[start + i];
        float4 q = pack[src];
        float t = q.z + adv;
        float w = __builtin_amdgcn_exp2f(fmaxf(t, NEG_SLOPE * t));
        den += w;
        a0 += w * q.x;
        a1 += w * q.y;
    }
#pragma unroll
    for (int off = 1; off < 64; off <<= 1) {
        den += __shfl_xor(den, off);
        a0  += __shfl_xor(a0, off);
        a1  += __shfl_xor(a1, off);
    }
    if (lane == 0) {
        float t = self.z + adv;                      // self loop
        float w = __builtin_amdgcn_exp2f(fmaxf(t, NEG_SLOPE * t));
        den += w;
        a0 += w * self.x;
        a1 += w * self.y;
        float o0 = a0 / den + b2[0];
        float o1 = a1 / den + b2[1];
        float m = fmaxf(o0, o1);
        float lse = m + logf(__expf(o0 - m) + __expf(o1 - m));
        out[n * 2 + 0] = o0 - lse;
        out[n * 2 + 1] = o1 - lse;
    }
}

// ---------------------------------------------------------------------------
extern "C" void kernel_launch(void* const* d_in, const int* in_sizes, int n_in,
                              void* d_out, int out_size, void* d_ws, size_t ws_size,
                              hipStream_t stream) {
    const float* x     = (const float*)d_in[0];
    const int*   ei    = (const int*)d_in[1];
    const float* W1    = (const float*)d_in[2];
    const float* as1w  = (const float*)d_in[3];
    const float* ad1w  = (const float*)d_in[4];
    const float* b1    = (const float*)d_in[5];
    const float* W2    = (const float*)d_in[6];
    const float* as2w  = (const float*)d_in[7];
    const float* ad2w  = (const float*)d_in[8];
    const float* b2    = (const float*)d_in[9];
    float* out = (float*)d_out;

    const int N = in_sizes[0] / 7;
    const int E = in_sizes[1] / 2;
    const int* srcA = ei;
    const int* dstA = ei + E;
    const int NB = (N + ((1 << NPB_SHIFT) - 1)) >> NPB_SHIFT;

    size_t off = 0;
    auto alloc = [&](size_t bytes) -> void* {
        void* p = (char*)d_ws + off;
        off += (bytes + 255) & ~(size_t)255;
        return p;
    };
    // payload (4B/edge) is dead after k_buildcsr; rec (256B/node) aliases it.
    size_t payload_bytes = (size_t)E * 4;
    size_t rec_bytes = (size_t)N * 256;
    unsigned int* payload =
        (unsigned int*)alloc(payload_bytes > rec_bytes ? payload_bytes : rec_bytes);
    char* rec = (char*)payload;
    float* ad1  = (float*)alloc((size_t)N * 8 * 4);
    float4* pack = (float4*)alloc((size_t)N * 16);
    int*   deg  = (int*)alloc((size_t)N * 4);
    int*   rows = (int*)alloc((size_t)N * 4);
    int*   csr  = (int*)alloc((size_t)E * 4);
    int*   gcount       = (int*)alloc(NBMAX * 4);
    int*   bucket_start = (int*)alloc((NBMAX + 1) * 4);
    int*   cursor_g     = (int*)alloc(NBMAX * 4);

    hipMemsetAsync(gcount, 0, NBMAX * 4, stream);

    const int nb = (N + 3) / 4;
    const int sb = (E + SC_EDGES - 1) / SC_EDGES;

    k_hist<<<1024, 256, 0, stream>>>(dstA, E, NB, gcount);
    k_bscan<<<1, NBMAX, 0, stream>>>(gcount, NB, bucket_start, cursor_g);
    k_scatter<<<sb, 256, 0, stream>>>(srcA, dstA, E, NB, cursor_g, payload);
    k_buildcsr<<<NB, 1024, 0, stream>>>(payload, bucket_start, N, deg, rows, csr);

    k_h1<<<nb, 256, 0, stream>>>(x, W1, as1w, ad1w, N, rec, ad1);
    k_agg1<<<nb, 256, 0, stream>>>(rec, ad1, deg, rows, csr, b1,
                                   W2, as2w, ad2w, N, pack);
    k_agg2<<<nb, 256, 0, stream>>>(pack, deg, rows, csr, b2, N, out);
}